// Round 1
// baseline (44399.316 us; speedup 1.0000x reference)
//
#include <hip/hip_runtime.h>
#include <hip/hip_cooperative_groups.h>

namespace cg = cooperative_groups;

// Problem sizes (fixed by the reference)
#define TT 512
#define BB 64
#define II 1024
#define HH 1024
#define GG 3072   // 3*H

static const size_t GX_ELEMS = (size_t)TT * BB * GG;   // 100,663,296 floats = 402,653,184 B
static const size_t HS_ELEMS = (size_t)TT * BB * HH;   //  33,554,432 floats = 134,217,728 B

// ---------------------------------------------------------------------------
// Kernel 1: gx[t][b][g] = sum_i x[b,t,i] * w_ih[g,i]
// C rows = t*64+b (row-major [32768][3072]); block tile 64x64, BK=32,
// 256 threads, 4x4 per-thread microtile. grid = (48 g-tiles, 512 t)
// ---------------------------------------------------------------------------
#define BK 32
__global__ __launch_bounds__(256) void gx_gemm(const float* __restrict__ x,
                                               const float* __restrict__ w_ih,
                                               float* __restrict__ gx) {
    __shared__ float As[BK][68];   // [k][m], padded: stride 68 floats (16B-aligned rows)
    __shared__ float Bs[BK][68];   // [k][n]
    const int tid = threadIdx.x;
    const int bx = blockIdx.x;     // g tile
    const int by = blockIdx.y;     // t
    const int tx = tid & 15, ty = tid >> 4;
    float acc[4][4] = {};

    for (int k0 = 0; k0 < II; k0 += BK) {
        #pragma unroll
        for (int i = 0; i < 2; ++i) {
            int f = tid + 256 * i;          // [0,512): 64 rows x 8 float4
            int row = f >> 3, kq = f & 7;
            // A row = b index; t = by. x[b][t][k]
            float4 v = *(const float4*)&x[((size_t)row * TT + by) * II + k0 + kq * 4];
            As[kq*4+0][row] = v.x; As[kq*4+1][row] = v.y;
            As[kq*4+2][row] = v.z; As[kq*4+3][row] = v.w;
            float4 w = *(const float4*)&w_ih[(size_t)(bx*64 + row) * II + k0 + kq * 4];
            Bs[kq*4+0][row] = w.x; Bs[kq*4+1][row] = w.y;
            Bs[kq*4+2][row] = w.z; Bs[kq*4+3][row] = w.w;
        }
        __syncthreads();
        #pragma unroll
        for (int kk = 0; kk < BK; ++kk) {
            float4 a4 = *(const float4*)&As[kk][ty*4];
            float4 b4 = *(const float4*)&Bs[kk][tx*4];
            float a[4] = {a4.x, a4.y, a4.z, a4.w};
            float b[4] = {b4.x, b4.y, b4.z, b4.w};
            #pragma unroll
            for (int i = 0; i < 4; ++i)
                #pragma unroll
                for (int j = 0; j < 4; ++j)
                    acc[i][j] = fmaf(a[i], b[j], acc[i][j]);
        }
        __syncthreads();
    }
    #pragma unroll
    for (int i = 0; i < 4; ++i) {
        float4 o = make_float4(acc[i][0], acc[i][1], acc[i][2], acc[i][3]);
        *(float4*)&gx[(size_t)(by*64 + ty*4 + i) * GG + bx*64 + tx*4] = o;
    }
}

// ---------------------------------------------------------------------------
// Kernel 2: the recurrent scan (cooperative, 256 blocks x 256 threads).
// Block owns 4 consecutive h-columns j (XCD-swizzled so adjacent-j blocks
// share an XCD). Thread = (b = tid&63, jl = tid>>6). Per step:
//   gh[b][{j,H+j,2H+j}] = sum_k h_prev[b][k] * w_hh[row][k]
// w_hh rows for this block (12 rows, 48KB) staged in LDS once.
// h_prev staged per 64-wide k-chunk into a swizzled LDS tile:
//   hsT[kl][ b ^ (kl>>2) ]  -> conflict-free transposing writes AND reads.
// h state history hs[t][b][k] is written to global ws (read by next step +
// final projection GEMM).
// ---------------------------------------------------------------------------
__device__ __forceinline__ float sig_(float x) {
    return 1.f / (1.f + __expf(-x));
}
__device__ __forceinline__ float tanh_(float x) {
    x = fminf(20.f, fmaxf(-20.f, x));
    float e = __expf(-2.f * x);
    return (1.f - e) / (1.f + e);
}

__global__ __launch_bounds__(256) void scan_kernel(const float* __restrict__ gx,
                                                   const float* __restrict__ w_hh,
                                                   float* __restrict__ hs) {
    __shared__ float wlds[12 * 1024];   // 48 KB: rows (gate*4 + jl)
    __shared__ float hsT[64 * 64];      // 16 KB: swizzled h chunk
    const int tid = threadIdx.x;
    const int bid = blockIdx.x;
    const int b  = tid & 63;
    const int jl = tid >> 6;                        // wave-uniform
    const int jblk = (bid & 7) * 32 + (bid >> 3);   // XCD-contiguous j blocks
    const int j = jblk * 4 + jl;

    // stage w_hh rows {j, H+j, 2H+j} for jl=0..3 -> wlds[(gate*4+jj)*1024 + k]
    #pragma unroll
    for (int i = 0; i < 12; ++i) {
        int f = tid + 256 * i;          // [0,3072): 12 rows x 256 float4
        int row = f >> 8;               // [0,12)
        int kq = f & 255;
        int gate = row >> 2, jj = row & 3;
        float4 v = *(const float4*)&w_hh[((size_t)gate * HH + jblk*4 + jj) * HH + kq*4];
        *(float4*)&wlds[row * 1024 + kq*4] = v;
    }
    __syncthreads();

    const float* wr = &wlds[(0 + jl) * 1024];
    const float* wz = &wlds[(4 + jl) * 1024];
    const float* wn = &wlds[(8 + jl) * 1024];

    cg::grid_group grid = cg::this_grid();

    for (int t = 0; t < TT; ++t) {
        float gr = 0.f, gz = 0.f, gn = 0.f;
        const float* __restrict__ hprev = hs + (size_t)(t > 0 ? t - 1 : 0) * (BB * HH);
        if (t > 0) {
            for (int c = 0; c < HH; c += 64) {
                // stage 64b x 64k chunk, transposed + swizzled
                #pragma unroll
                for (int i = 0; i < 4; ++i) {
                    int f = tid + 256 * i;      // [0,1024): 64 rows x 16 float4
                    int k4 = f & 15;
                    int brow = f >> 4;
                    float4 v = *(const float4*)&hprev[(size_t)brow * HH + c + k4*4];
                    int col = brow ^ k4;        // swizzle f(kl) = kl>>2
                    hsT[(k4*4+0)*64 + col] = v.x;
                    hsT[(k4*4+1)*64 + col] = v.y;
                    hsT[(k4*4+2)*64 + col] = v.z;
                    hsT[(k4*4+3)*64 + col] = v.w;
                }
                __syncthreads();
                #pragma unroll
                for (int kq = 0; kq < 16; ++kq) {
                    float4 wr4 = *(const float4*)&wr[c + kq*4];
                    float4 wz4 = *(const float4*)&wz[c + kq*4];
                    float4 wn4 = *(const float4*)&wn[c + kq*4];
                    int col = b ^ kq;
                    float h0 = hsT[(kq*4+0)*64 + col];
                    float h1 = hsT[(kq*4+1)*64 + col];
                    float h2 = hsT[(kq*4+2)*64 + col];
                    float h3 = hsT[(kq*4+3)*64 + col];
                    gr = fmaf(h0, wr4.x, gr); gr = fmaf(h1, wr4.y, gr);
                    gr = fmaf(h2, wr4.z, gr); gr = fmaf(h3, wr4.w, gr);
                    gz = fmaf(h0, wz4.x, gz); gz = fmaf(h1, wz4.y, gz);
                    gz = fmaf(h2, wz4.z, gz); gz = fmaf(h3, wz4.w, gz);
                    gn = fmaf(h0, wn4.x, gn); gn = fmaf(h1, wn4.y, gn);
                    gn = fmaf(h2, wn4.z, gn); gn = fmaf(h3, wn4.w, gn);
                }
                __syncthreads();
            }
        }
        // gates
        size_t gxoff = (size_t)t * (BB * GG) + (size_t)b * GG + j;
        float gxr = gx[gxoff];
        float gxz = gx[gxoff + HH];
        float gxn = gx[gxoff + 2 * HH];
        float hold = (t > 0) ? hprev[(size_t)b * HH + j] : 0.f;
        float r = sig_(gxr + gr);
        float z = sig_(gxz + gz);
        float n = tanh_(gxn + r * gn);
        float hnew = (1.f - z) * n + z * hold;
        hs[(size_t)t * (BB * HH) + (size_t)b * HH + j] = hnew;
        grid.sync();
    }
}

// ---------------------------------------------------------------------------
// Kernel 3: out[b][t][g] = sum_k hs[t][b][k] * w_proj[g][k]
// A rows = t*64+b (hs row-major), same GEMM structure as gx_gemm,
// store transposed to out[b][t][g]. grid = (16 g-tiles, 512 t)
// ---------------------------------------------------------------------------
__global__ __launch_bounds__(256) void proj_gemm(const float* __restrict__ hs,
                                                 const float* __restrict__ w_proj,
                                                 float* __restrict__ out) {
    __shared__ float As[BK][68];
    __shared__ float Bs[BK][68];
    const int tid = threadIdx.x;
    const int bx = blockIdx.x;     // g tile (16)
    const int by = blockIdx.y;     // t (512)
    const int tx = tid & 15, ty = tid >> 4;
    float acc[4][4] = {};

    for (int k0 = 0; k0 < HH; k0 += BK) {
        #pragma unroll
        for (int i = 0; i < 2; ++i) {
            int f = tid + 256 * i;
            int row = f >> 3, kq = f & 7;
            float4 v = *(const float4*)&hs[((size_t)by * 64 + row) * HH + k0 + kq * 4];
            As[kq*4+0][row] = v.x; As[kq*4+1][row] = v.y;
            As[kq*4+2][row] = v.z; As[kq*4+3][row] = v.w;
            float4 w = *(const float4*)&w_proj[(size_t)(bx*64 + row) * HH + k0 + kq * 4];
            Bs[kq*4+0][row] = w.x; Bs[kq*4+1][row] = w.y;
            Bs[kq*4+2][row] = w.z; Bs[kq*4+3][row] = w.w;
        }
        __syncthreads();
        #pragma unroll
        for (int kk = 0; kk < BK; ++kk) {
            float4 a4 = *(const float4*)&As[kk][ty*4];
            float4 b4 = *(const float4*)&Bs[kk][tx*4];
            float a[4] = {a4.x, a4.y, a4.z, a4.w};
            float b[4] = {b4.x, b4.y, b4.z, b4.w};
            #pragma unroll
            for (int i = 0; i < 4; ++i)
                #pragma unroll
                for (int jj = 0; jj < 4; ++jj)
                    acc[i][jj] = fmaf(a[i], b[jj], acc[i][jj]);
        }
        __syncthreads();
    }
    // row = by*64 + (ty*4+i) = t*64 + b  ->  out[b][t][g]
    #pragma unroll
    for (int i = 0; i < 4; ++i) {
        float4 o = make_float4(acc[i][0], acc[i][1], acc[i][2], acc[i][3]);
        *(float4*)&out[((size_t)(ty*4 + i) * TT + by) * HH + bx*64 + tx*4] = o;
    }
}

// ---------------------------------------------------------------------------
extern "C" void kernel_launch(void* const* d_in, const int* in_sizes, int n_in,
                              void* d_out, int out_size, void* d_ws, size_t ws_size,
                              hipStream_t stream) {
    const float* x      = (const float*)d_in[0];
    const float* w_ih   = (const float*)d_in[1];
    const float* w_hh   = (const float*)d_in[2];
    const float* w_proj = (const float*)d_in[3];
    float* out = (float*)d_out;

    if (ws_size < (GX_ELEMS + HS_ELEMS) * sizeof(float)) return;  // need 512 MB

    float* gxbuf = (float*)d_ws;
    float* hsbuf = gxbuf + GX_ELEMS;

    gx_gemm<<<dim3(48, 512), 256, 0, stream>>>(x, w_ih, gxbuf);

    const float* gx_p = gxbuf;
    const float* whh_p = w_hh;
    float* hs_p = hsbuf;
    void* args[] = {(void*)&gx_p, (void*)&whh_p, (void*)&hs_p};
    hipLaunchCooperativeKernel((void*)scan_kernel, dim3(256), dim3(256), args, 0, stream);

    proj_gemm<<<dim3(16, 512), 256, 0, stream>>>(hsbuf, w_proj, out);
}

// Round 2
// 26455.557 us; speedup vs baseline: 1.6783x; 1.6783x over previous
//
#include <hip/hip_runtime.h>
#include <hip/hip_cooperative_groups.h>

namespace cg = cooperative_groups;

// Problem sizes (fixed by the reference)
#define TT 512
#define BB 64
#define II 1024
#define HH 1024
#define GG 3072   // 3*H

static const size_t GX_ELEMS = (size_t)TT * BB * GG;   // 402 MB fp32 (gxT[t][g][b])
static const size_t HS_ELEMS = (size_t)TT * BB * HH;   // 134 MB fp32 (hsT[t][k][b])

// ---------------------------------------------------------------------------
// Kernel 1: gxT[t][g][b] = sum_i x[b,t,i] * w_ih[g,i]   (TRANSPOSED output:
// b is the fastest dim so the scan's per-lane reads are coalesced).
// Block tile: 64 b x 64 g, BK=32, 256 threads, 4x4 microtile.
// grid = (48 g-tiles, 512 t)
// ---------------------------------------------------------------------------
#define BK 32
__global__ __launch_bounds__(256) void gx_gemm(const float* __restrict__ x,
                                               const float* __restrict__ w_ih,
                                               float* __restrict__ gxT) {
    __shared__ float As[BK][68];   // [k][b], padded rows
    __shared__ float Bs[BK][68];   // [k][g]
    const int tid = threadIdx.x;
    const int bx = blockIdx.x;     // g tile
    const int by = blockIdx.y;     // t
    const int tx = tid & 15, ty = tid >> 4;
    float acc[4][4] = {};

    for (int k0 = 0; k0 < II; k0 += BK) {
        #pragma unroll
        for (int i = 0; i < 2; ++i) {
            int f = tid + 256 * i;          // [0,512): 64 rows x 8 float4
            int row = f >> 3, kq = f & 7;
            // A row = b index; t = by. x[b][t][k]
            float4 v = *(const float4*)&x[((size_t)row * TT + by) * II + k0 + kq * 4];
            As[kq*4+0][row] = v.x; As[kq*4+1][row] = v.y;
            As[kq*4+2][row] = v.z; As[kq*4+3][row] = v.w;
            float4 w = *(const float4*)&w_ih[(size_t)(bx*64 + row) * II + k0 + kq * 4];
            Bs[kq*4+0][row] = w.x; Bs[kq*4+1][row] = w.y;
            Bs[kq*4+2][row] = w.z; Bs[kq*4+3][row] = w.w;
        }
        __syncthreads();
        #pragma unroll
        for (int kk = 0; kk < BK; ++kk) {
            float4 a4 = *(const float4*)&As[kk][ty*4];
            float4 b4 = *(const float4*)&Bs[kk][tx*4];
            float a[4] = {a4.x, a4.y, a4.z, a4.w};
            float b[4] = {b4.x, b4.y, b4.z, b4.w};
            #pragma unroll
            for (int i = 0; i < 4; ++i)
                #pragma unroll
                for (int j = 0; j < 4; ++j)
                    acc[i][j] = fmaf(a[i], b[j], acc[i][j]);
        }
        __syncthreads();
    }
    // transposed store: gxT[(t*GG + g)*64 + b]; acc[i][j] -> b = ty*4+i, g = bx*64+tx*4+j
    #pragma unroll
    for (int j = 0; j < 4; ++j) {
        float4 o = make_float4(acc[0][j], acc[1][j], acc[2][j], acc[3][j]);
        *(float4*)&gxT[((size_t)by * GG + bx*64 + tx*4 + j) * 64 + ty*4] = o;
    }
}

// ---------------------------------------------------------------------------
// Kernel 2: recurrent scan (cooperative, 256 blocks x 512 threads).
// Block owns 4 consecutive h-columns j (XCD-swizzled). Thread = (b = tid&63,
// kh = tid>>6 in [0,8)). Each thread accumulates ALL 12 gate rows
// (3 gates x 4 jl) over its 128-wide k-slice: 12 FMA per h-load, no
// duplicate h traffic, no LDS staging of h (hsT reads are lane-coalesced).
// w_hh rows for this block (12 rows, 48KB) staged in LDS once, broadcast
// reads. Per-step: k-loop -> LDS kh-reduction -> gate epilogue -> grid.sync.
// ---------------------------------------------------------------------------
__device__ __forceinline__ float sig_(float x) {
    return 1.f / (1.f + __expf(-x));
}
__device__ __forceinline__ float tanh_(float x) {
    x = fminf(20.f, fmaxf(-20.f, x));
    float e = __expf(-2.f * x);
    return (1.f - e) / (1.f + e);
}

__global__ __launch_bounds__(512) void scan_kernel(const float* __restrict__ gxT,
                                                   const float* __restrict__ w_hh,
                                                   float* __restrict__ hsT) {
    __shared__ float wlds[12 * 1024];   // 48 KB: row r = gate*4 + jj
    __shared__ float red[8][12][64];    // 24 KB: [kh][row][b]
    const int tid = threadIdx.x;
    const int bid = blockIdx.x;
    const int b  = tid & 63;
    const int kh = tid >> 6;                        // wave-uniform, [0,8)
    const int jblk = (bid & 7) * 32 + (bid >> 3);   // XCD-contiguous j blocks
    const int jl = kh & 3;                          // reused thread id for epilogue
    const int j  = jblk * 4 + jl;

    // stage w_hh rows {gate*H + jblk*4 + jj} -> wlds[(gate*4+jj)*1024 + k]
    #pragma unroll
    for (int i = 0; i < 6; ++i) {
        int f = tid + 512 * i;          // [0,3072): 12 rows x 256 float4
        int row = f >> 8;               // [0,12)
        int kq = f & 255;
        float4 v = *(const float4*)&w_hh[((size_t)(row >> 2) * HH + jblk*4 + (row & 3)) * HH + kq*4];
        *(float4*)&wlds[row * 1024 + kq*4] = v;
    }
    __syncthreads();

    cg::grid_group grid = cg::this_grid();

    for (int t = 0; t < TT; ++t) {
        float acc[12] = {};
        if (t > 0) {
            const float* __restrict__ hp = hsT + (size_t)(t - 1) * (HH * 64);
            #pragma unroll 2
            for (int kq = 0; kq < 32; ++kq) {
                int kk = kh * 128 + kq * 4;
                const float* hpk = hp + (size_t)kk * 64 + b;
                float h0 = hpk[0];
                float h1 = hpk[64];
                float h2 = hpk[128];
                float h3 = hpk[192];
                #pragma unroll
                for (int r = 0; r < 12; ++r) {
                    float4 w4 = *(const float4*)&wlds[r * 1024 + kk];
                    acc[r] = fmaf(h0, w4.x, acc[r]);
                    acc[r] = fmaf(h1, w4.y, acc[r]);
                    acc[r] = fmaf(h2, w4.z, acc[r]);
                    acc[r] = fmaf(h3, w4.w, acc[r]);
                }
            }
        }
        #pragma unroll
        for (int r = 0; r < 12; ++r) red[kh][r][b] = acc[r];
        __syncthreads();

        if (tid < 256) {
            float gr = 0.f, gz = 0.f, gn = 0.f;
            #pragma unroll
            for (int k2 = 0; k2 < 8; ++k2) {
                gr += red[k2][0 + jl][b];
                gz += red[k2][4 + jl][b];
                gn += red[k2][8 + jl][b];
            }
            size_t gxoff = ((size_t)t * GG + j) * 64 + b;
            float gxr = gxT[gxoff];
            float gxz = gxT[gxoff + (size_t)HH * 64];
            float gxn = gxT[gxoff + (size_t)2 * HH * 64];
            float hold = (t > 0) ? hsT[((size_t)(t - 1) * HH + j) * 64 + b] : 0.f;
            float r = sig_(gxr + gr);
            float z = sig_(gxz + gz);
            float n = tanh_(gxn + r * gn);
            float hnew = (1.f - z) * n + z * hold;
            hsT[((size_t)t * HH + j) * 64 + b] = hnew;
        }
        grid.sync();
    }
}

// ---------------------------------------------------------------------------
// Kernel 3: out[b][t][g] = sum_k hsT[t][k][b] * w_proj[g][k]
// A is already [k][b] per t -> pure coalesced copy into LDS, no transpose.
// grid = (16 g-tiles, 512 t)
// ---------------------------------------------------------------------------
__global__ __launch_bounds__(256) void proj_gemm(const float* __restrict__ hsT,
                                                 const float* __restrict__ w_proj,
                                                 float* __restrict__ out) {
    __shared__ float As[BK][64];   // [k][b] direct copy (sequential writes, no pad needed)
    __shared__ float Bs[BK][68];   // [k][g] transposed from w_proj rows
    const int tid = threadIdx.x;
    const int bx = blockIdx.x;     // g tile (16)
    const int by = blockIdx.y;     // t (512)
    const int tx = tid & 15, ty = tid >> 4;
    float acc[4][4] = {};

    for (int k0 = 0; k0 < HH; k0 += BK) {
        #pragma unroll
        for (int i = 0; i < 2; ++i) {
            int f = tid + 256 * i;          // [0,512): 32 k-rows x 16 float4
            int krow = f >> 4, b4 = f & 15;
            float4 v = *(const float4*)&hsT[((size_t)by * HH + k0 + krow) * 64 + b4 * 4];
            *(float4*)&As[krow][b4 * 4] = v;
            int wrow = f >> 3, kq = f & 7;  // [0,512): 64 g-rows x 8 float4
            float4 w = *(const float4*)&w_proj[(size_t)(bx*64 + wrow) * HH + k0 + kq * 4];
            Bs[kq*4+0][wrow] = w.x; Bs[kq*4+1][wrow] = w.y;
            Bs[kq*4+2][wrow] = w.z; Bs[kq*4+3][wrow] = w.w;
        }
        __syncthreads();
        #pragma unroll
        for (int kk = 0; kk < BK; ++kk) {
            float4 a4 = *(const float4*)&As[kk][ty*4];
            float4 b4 = *(const float4*)&Bs[kk][tx*4];
            float a[4] = {a4.x, a4.y, a4.z, a4.w};
            float b[4] = {b4.x, b4.y, b4.z, b4.w};
            #pragma unroll
            for (int i = 0; i < 4; ++i)
                #pragma unroll
                for (int jj = 0; jj < 4; ++jj)
                    acc[i][jj] = fmaf(a[i], b[jj], acc[i][jj]);
        }
        __syncthreads();
    }
    // acc[i][j]: b = ty*4+i, g = bx*64+tx*4+j; out[b][t][g]
    #pragma unroll
    for (int i = 0; i < 4; ++i) {
        float4 o = make_float4(acc[i][0], acc[i][1], acc[i][2], acc[i][3]);
        *(float4*)&out[((size_t)(ty*4 + i) * TT + by) * HH + bx*64 + tx*4] = o;
    }
}

// ---------------------------------------------------------------------------
extern "C" void kernel_launch(void* const* d_in, const int* in_sizes, int n_in,
                              void* d_out, int out_size, void* d_ws, size_t ws_size,
                              hipStream_t stream) {
    const float* x      = (const float*)d_in[0];
    const float* w_ih   = (const float*)d_in[1];
    const float* w_hh   = (const float*)d_in[2];
    const float* w_proj = (const float*)d_in[3];
    float* out = (float*)d_out;

    if (ws_size < (GX_ELEMS + HS_ELEMS) * sizeof(float)) return;  // need 512 MB

    float* gxbuf = (float*)d_ws;
    float* hsbuf = gxbuf + GX_ELEMS;

    gx_gemm<<<dim3(48, 512), 256, 0, stream>>>(x, w_ih, gxbuf);

    const float* gx_p = gxbuf;
    const float* whh_p = w_hh;
    float* hs_p = hsbuf;
    void* args[] = {(void*)&gx_p, (void*)&whh_p, (void*)&hs_p};
    hipLaunchCooperativeKernel((void*)scan_kernel, dim3(256), dim3(512), args, 0, stream);

    proj_gemm<<<dim3(16, 512), 256, 0, stream>>>(hsbuf, w_proj, out);
}

// Round 3
// 24383.873 us; speedup vs baseline: 1.8208x; 1.0850x over previous
//
#include <hip/hip_runtime.h>
#include <hip/hip_cooperative_groups.h>

namespace cg = cooperative_groups;

// Problem sizes (fixed by the reference)
#define TT 512
#define BB 64
#define II 1024
#define HH 1024
#define GG 3072   // 3*H

static const size_t GX_ELEMS = (size_t)TT * BB * GG;   // 402 MB fp32 (gxT[t][g][b])
static const size_t HS_ELEMS = (size_t)TT * BB * HH;   // 134 MB fp32 (hsT2[t][k/4][b][4])

// ---------------------------------------------------------------------------
// Kernel 1: gxT[t][g][b] = sum_i x[b,t,i] * w_ih[g,i]   (b fastest).
// Block tile: 64 b x 64 g, BK=32, 256 threads, 4x4 microtile.
// grid = (48 g-tiles, 512 t)
// ---------------------------------------------------------------------------
#define BK 32
__global__ __launch_bounds__(256) void gx_gemm(const float* __restrict__ x,
                                               const float* __restrict__ w_ih,
                                               float* __restrict__ gxT) {
    __shared__ float As[BK][68];   // [k][b], padded rows
    __shared__ float Bs[BK][68];   // [k][g]
    const int tid = threadIdx.x;
    const int bx = blockIdx.x;     // g tile
    const int by = blockIdx.y;     // t
    const int tx = tid & 15, ty = tid >> 4;
    float acc[4][4] = {};

    for (int k0 = 0; k0 < II; k0 += BK) {
        #pragma unroll
        for (int i = 0; i < 2; ++i) {
            int f = tid + 256 * i;          // [0,512): 64 rows x 8 float4
            int row = f >> 3, kq = f & 7;
            float4 v = *(const float4*)&x[((size_t)row * TT + by) * II + k0 + kq * 4];
            As[kq*4+0][row] = v.x; As[kq*4+1][row] = v.y;
            As[kq*4+2][row] = v.z; As[kq*4+3][row] = v.w;
            float4 w = *(const float4*)&w_ih[(size_t)(bx*64 + row) * II + k0 + kq * 4];
            Bs[kq*4+0][row] = w.x; Bs[kq*4+1][row] = w.y;
            Bs[kq*4+2][row] = w.z; Bs[kq*4+3][row] = w.w;
        }
        __syncthreads();
        #pragma unroll
        for (int kk = 0; kk < BK; ++kk) {
            float4 a4 = *(const float4*)&As[kk][ty*4];
            float4 b4 = *(const float4*)&Bs[kk][tx*4];
            float a[4] = {a4.x, a4.y, a4.z, a4.w};
            float b[4] = {b4.x, b4.y, b4.z, b4.w};
            #pragma unroll
            for (int i = 0; i < 4; ++i)
                #pragma unroll
                for (int j = 0; j < 4; ++j)
                    acc[i][j] = fmaf(a[i], b[j], acc[i][j]);
        }
        __syncthreads();
    }
    #pragma unroll
    for (int j = 0; j < 4; ++j) {
        float4 o = make_float4(acc[0][j], acc[1][j], acc[2][j], acc[3][j]);
        *(float4*)&gxT[((size_t)by * GG + bx*64 + tx*4 + j) * 64 + ty*4] = o;
    }
}

// ---------------------------------------------------------------------------
// Custom two-level grid barrier (state in d_out, zeroed before launch).
// Monotonic epoch counters: no reset races. 32 arrivals per XCD-group line,
// then 8 to a global line, then one release word all blocks spin on.
// ---------------------------------------------------------------------------
__device__ __forceinline__ void grid_barrier(unsigned* sync, int bid, unsigned e) {
    // layout (uints): cnt[g] at g*32 (g<8, 128B apart), gcnt at 256, rel at 288
    unsigned* cnt  = sync + (bid & 7) * 32;
    unsigned* gcnt = sync + 256;
    unsigned* rel  = sync + 288;
    __threadfence();   // publish this block's stores device-wide (L2 writeback)
    unsigned old = __hip_atomic_fetch_add(cnt, 1u, __ATOMIC_ACQ_REL, __HIP_MEMORY_SCOPE_AGENT);
    if (old == 32u * e - 1u) {                       // last arrival in group
        unsigned og = __hip_atomic_fetch_add(gcnt, 1u, __ATOMIC_ACQ_REL, __HIP_MEMORY_SCOPE_AGENT);
        if (og == 8u * e - 1u)                       // last group overall
            __hip_atomic_store(rel, e, __ATOMIC_RELEASE, __HIP_MEMORY_SCOPE_AGENT);
    }
    while (__hip_atomic_load(rel, __ATOMIC_ACQUIRE, __HIP_MEMORY_SCOPE_AGENT) < e)
        __builtin_amdgcn_s_sleep(1);
}

// ---------------------------------------------------------------------------
// Kernel 2: recurrent scan (256 blocks x 512 threads, persistent).
// Block owns 4 h-columns j (XCD-swizzled). Thread = (b = tid&63, kh = tid>>6).
// h history stored PACKED: hsT2[t][k>>2][b][k&3] -> each lane's h-read is one
// coalesced float4. w_hh rows (12, 48KB) in LDS; gx software-pipelined one
// step ahead; h_old carried in a register; custom grid barrier per step.
// ---------------------------------------------------------------------------
__device__ __forceinline__ float sig_(float x) {
    return 1.f / (1.f + __expf(-x));
}
__device__ __forceinline__ float tanh_(float x) {
    x = fminf(20.f, fmaxf(-20.f, x));
    float e = __expf(-2.f * x);
    return (1.f - e) / (1.f + e);
}

__global__ __launch_bounds__(512) void scan_kernel(const float* __restrict__ gxT,
                                                   const float* __restrict__ w_hh,
                                                   float* __restrict__ hsT2,
                                                   unsigned* __restrict__ sync) {
    __shared__ float wlds[12 * 1024];   // 48 KB: row r = gate*4 + jj
    __shared__ float red[8][12][64];    // 24 KB: [kh][row][b]
    const int tid = threadIdx.x;
    const int bid = blockIdx.x;
    const int b  = tid & 63;
    const int kh = tid >> 6;                        // wave-uniform, [0,8)
    const int jblk = (bid & 7) * 32 + (bid >> 3);   // XCD-contiguous j blocks
    const int jl = kh & 3;
    const int j  = jblk * 4 + jl;
    const bool epi = (tid < 256);

    // stage w_hh rows {gate*H + jblk*4 + jj} -> wlds[(gate*4+jj)*1024 + k]
    #pragma unroll
    for (int i = 0; i < 6; ++i) {
        int f = tid + 512 * i;          // [0,3072): 12 rows x 256 float4
        int row = f >> 8;               // [0,12)
        int kq = f & 255;
        float4 v = *(const float4*)&w_hh[((size_t)(row >> 2) * HH + jblk*4 + (row & 3)) * HH + kq*4];
        *(float4*)&wlds[row * 1024 + kq*4] = v;
    }
    __syncthreads();

    // software-pipelined gx registers (step t loaded during step t-1)
    float gx_r = 0.f, gx_z = 0.f, gx_n = 0.f;
    if (epi) {
        size_t off = (size_t)j * 64 + b;            // t = 0
        gx_r = gxT[off];
        gx_z = gxT[off + (size_t)HH * 64];
        gx_n = gxT[off + (size_t)2 * HH * 64];
    }
    float hold = 0.f;                               // h_{t-1}[b][j] register

    for (int t = 0; t < TT; ++t) {
        // prefetch next step's gx early (hidden under the k-loop)
        float nx_r = 0.f, nx_z = 0.f, nx_n = 0.f;
        if (epi && t + 1 < TT) {
            size_t off = ((size_t)(t + 1) * GG + j) * 64 + b;
            nx_r = gxT[off];
            nx_z = gxT[off + (size_t)HH * 64];
            nx_n = gxT[off + (size_t)2 * HH * 64];
        }

        float acc[12] = {};
        if (t > 0) {
            const float4* __restrict__ hp4 =
                (const float4*)hsT2 + (size_t)(t - 1) * ((HH / 4) * BB);
            #pragma unroll 4
            for (int k4 = 0; k4 < 32; ++k4) {
                int kk = (kh << 5) + k4;            // packed k4-block in [0,256)
                float4 h4 = hp4[kk * 64 + b];
                #pragma unroll
                for (int r = 0; r < 12; ++r) {
                    float4 w4 = *(const float4*)&wlds[r * 1024 + (kk << 2)];
                    acc[r] = fmaf(h4.x, w4.x, acc[r]);
                    acc[r] = fmaf(h4.y, w4.y, acc[r]);
                    acc[r] = fmaf(h4.z, w4.z, acc[r]);
                    acc[r] = fmaf(h4.w, w4.w, acc[r]);
                }
            }
        }
        #pragma unroll
        for (int r = 0; r < 12; ++r) red[kh][r][b] = acc[r];
        __syncthreads();

        if (epi) {
            float gr = 0.f, gz = 0.f, gn = 0.f;
            #pragma unroll
            for (int k2 = 0; k2 < 8; ++k2) {
                gr += red[k2][0 + jl][b];
                gz += red[k2][4 + jl][b];
                gn += red[k2][8 + jl][b];
            }
            float r = sig_(gx_r + gr);
            float z = sig_(gx_z + gz);
            float n = tanh_(gx_n + r * gn);
            float hnew = (1.f - z) * n + z * hold;
            // packed store: hsT2[t][jblk][b][jl]
            hsT2[(((size_t)t * 256 + jblk) * 64 + b) * 4 + jl] = hnew;
            hold = hnew;
        }
        __syncthreads();                            // all stores drained (vmcnt 0)

        if (t + 1 < TT) {
            if (tid == 0) grid_barrier(sync, bid, (unsigned)(t + 1));
            __syncthreads();
            if (epi) { gx_r = nx_r; gx_z = nx_z; gx_n = nx_n; }
        }
    }
}

// ---------------------------------------------------------------------------
// Kernel 3: out[b][t][g] = sum_k hsT2[t][k>>2][b][k&3] * w_proj[g][k]
// A-stage is a pure float4 copy of the packed layout. grid = (16, 512)
// ---------------------------------------------------------------------------
__global__ __launch_bounds__(256) void proj_gemm(const float* __restrict__ hsT2,
                                                 const float* __restrict__ w_proj,
                                                 float* __restrict__ out) {
    __shared__ float As2[8][64][4];   // [k4][b][ki] packed copy (8 KB)
    __shared__ float Bs[BK][68];      // [k][g]
    const int tid = threadIdx.x;
    const int bx = blockIdx.x;     // g tile (16)
    const int by = blockIdx.y;     // t (512)
    const int tx = tid & 15, ty = tid >> 4;
    float acc[4][4] = {};

    const float4* __restrict__ hp4 = (const float4*)hsT2 + (size_t)by * ((HH / 4) * BB);

    for (int k0 = 0; k0 < HH; k0 += BK) {
        #pragma unroll
        for (int i = 0; i < 2; ++i) {
            int f = tid + 256 * i;          // [0,512): 8 k4-blocks x 64 b
            int k4l = f >> 6, bb = f & 63;
            float4 v = hp4[((size_t)(k0 >> 2) + k4l) * 64 + bb];
            *(float4*)&As2[k4l][bb][0] = v;
            int wrow = f >> 3, kq = f & 7;  // [0,512): 64 g-rows x 8 float4
            float4 w = *(const float4*)&w_proj[(size_t)(bx*64 + wrow) * HH + k0 + kq * 4];
            Bs[kq*4+0][wrow] = w.x; Bs[kq*4+1][wrow] = w.y;
            Bs[kq*4+2][wrow] = w.z; Bs[kq*4+3][wrow] = w.w;
        }
        __syncthreads();
        #pragma unroll
        for (int k4 = 0; k4 < 8; ++k4) {
            float4 a4[4];
            #pragma unroll
            for (int i = 0; i < 4; ++i) a4[i] = *(const float4*)&As2[k4][ty*4 + i][0];
            float4 b4[4];
            #pragma unroll
            for (int kk = 0; kk < 4; ++kk) b4[kk] = *(const float4*)&Bs[k4*4 + kk][tx*4];
            #pragma unroll
            for (int i = 0; i < 4; ++i) {
                float a[4] = {a4[i].x, a4[i].y, a4[i].z, a4[i].w};
                #pragma unroll
                for (int jj = 0; jj < 4; ++jj) {
                    float bv[4] = {b4[0].x, b4[0].y, b4[0].z, b4[0].w};
                    // index b4[kk] component jj
                    float b0 = (jj == 0) ? b4[0].x : (jj == 1) ? b4[0].y : (jj == 2) ? b4[0].z : b4[0].w;
                    float b1 = (jj == 0) ? b4[1].x : (jj == 1) ? b4[1].y : (jj == 2) ? b4[1].z : b4[1].w;
                    float b2 = (jj == 0) ? b4[2].x : (jj == 1) ? b4[2].y : (jj == 2) ? b4[2].z : b4[2].w;
                    float b3 = (jj == 0) ? b4[3].x : (jj == 1) ? b4[3].y : (jj == 2) ? b4[3].z : b4[3].w;
                    (void)bv;
                    acc[i][jj] = fmaf(a[0], b0, acc[i][jj]);
                    acc[i][jj] = fmaf(a[1], b1, acc[i][jj]);
                    acc[i][jj] = fmaf(a[2], b2, acc[i][jj]);
                    acc[i][jj] = fmaf(a[3], b3, acc[i][jj]);
                }
            }
        }
        __syncthreads();
    }
    #pragma unroll
    for (int i = 0; i < 4; ++i) {
        float4 o = make_float4(acc[i][0], acc[i][1], acc[i][2], acc[i][3]);
        *(float4*)&out[((size_t)(ty*4 + i) * TT + by) * HH + bx*64 + tx*4] = o;
    }
}

// ---------------------------------------------------------------------------
extern "C" void kernel_launch(void* const* d_in, const int* in_sizes, int n_in,
                              void* d_out, int out_size, void* d_ws, size_t ws_size,
                              hipStream_t stream) {
    const float* x      = (const float*)d_in[0];
    const float* w_ih   = (const float*)d_in[1];
    const float* w_hh   = (const float*)d_in[2];
    const float* w_proj = (const float*)d_in[3];
    float* out = (float*)d_out;

    if (ws_size < (GX_ELEMS + HS_ELEMS) * sizeof(float)) return;  // need 512 MB

    float* gxbuf = (float*)d_ws;
    float* hsbuf = gxbuf + GX_ELEMS;

    // barrier state lives in d_out (proj overwrites it afterwards)
    hipMemsetAsync(d_out, 0, 4096, stream);

    gx_gemm<<<dim3(48, 512), 256, 0, stream>>>(x, w_ih, gxbuf);

    const float* gx_p = gxbuf;
    const float* whh_p = w_hh;
    float* hs_p = hsbuf;
    unsigned* sync_p = (unsigned*)d_out;
    void* args[] = {(void*)&gx_p, (void*)&whh_p, (void*)&hs_p, (void*)&sync_p};
    hipLaunchCooperativeKernel((void*)scan_kernel, dim3(256), dim3(512), args, 0, stream);

    proj_gemm<<<dim3(16, 512), 256, 0, stream>>>(hsbuf, w_proj, out);
}

// Round 4
// 13410.190 us; speedup vs baseline: 3.3109x; 1.8183x over previous
//
#include <hip/hip_runtime.h>
#include <hip/hip_cooperative_groups.h>

namespace cg = cooperative_groups;

// Problem sizes (fixed by the reference)
#define TT 512
#define BB 64
#define II 1024
#define HH 1024
#define GG 3072   // 3*H

static const size_t GX_ELEMS = (size_t)TT * BB * GG;   // 402 MB fp32 (gxT[t][g][b])
static const size_t HS_ELEMS = (size_t)TT * BB * HH;   // 134 MB fp32 (hsT2[t][k/4][b][4])

// ---------------------------------------------------------------------------
// Kernel 1: gxT[t][g][b] = sum_i x[b,t,i] * w_ih[g,i]   (b fastest).
// ---------------------------------------------------------------------------
#define BK 32
__global__ __launch_bounds__(256) void gx_gemm(const float* __restrict__ x,
                                               const float* __restrict__ w_ih,
                                               float* __restrict__ gxT) {
    __shared__ float As[BK][68];   // [k][b], padded rows
    __shared__ float Bs[BK][68];   // [k][g]
    const int tid = threadIdx.x;
    const int bx = blockIdx.x;     // g tile
    const int by = blockIdx.y;     // t
    const int tx = tid & 15, ty = tid >> 4;
    float acc[4][4] = {};

    for (int k0 = 0; k0 < II; k0 += BK) {
        #pragma unroll
        for (int i = 0; i < 2; ++i) {
            int f = tid + 256 * i;          // [0,512): 64 rows x 8 float4
            int row = f >> 3, kq = f & 7;
            float4 v = *(const float4*)&x[((size_t)row * TT + by) * II + k0 + kq * 4];
            As[kq*4+0][row] = v.x; As[kq*4+1][row] = v.y;
            As[kq*4+2][row] = v.z; As[kq*4+3][row] = v.w;
            float4 w = *(const float4*)&w_ih[(size_t)(bx*64 + row) * II + k0 + kq * 4];
            Bs[kq*4+0][row] = w.x; Bs[kq*4+1][row] = w.y;
            Bs[kq*4+2][row] = w.z; Bs[kq*4+3][row] = w.w;
        }
        __syncthreads();
        #pragma unroll
        for (int kk = 0; kk < BK; ++kk) {
            float4 a4 = *(const float4*)&As[kk][ty*4];
            float4 b4 = *(const float4*)&Bs[kk][tx*4];
            float a[4] = {a4.x, a4.y, a4.z, a4.w};
            float b[4] = {b4.x, b4.y, b4.z, b4.w};
            #pragma unroll
            for (int i = 0; i < 4; ++i)
                #pragma unroll
                for (int j = 0; j < 4; ++j)
                    acc[i][j] = fmaf(a[i], b[j], acc[i][j]);
        }
        __syncthreads();
    }
    #pragma unroll
    for (int j = 0; j < 4; ++j) {
        float4 o = make_float4(acc[0][j], acc[1][j], acc[2][j], acc[3][j]);
        *(float4*)&gxT[((size_t)by * GG + bx*64 + tx*4 + j) * 64 + ty*4] = o;
    }
}

// ---------------------------------------------------------------------------
// Custom two-level grid barrier. Minimal cache maintenance: ONE release
// fence (wbL2) before arrival, RELAXED polls, ONE acquire fence (inv) after
// the release is observed. State in d_out (zeroed before launch).
// ---------------------------------------------------------------------------
__device__ __forceinline__ void grid_barrier(unsigned* sync, int bid, unsigned e) {
    unsigned* cnt  = sync + (bid & 7) * 32;   // 8 groups, 128B apart
    unsigned* gcnt = sync + 256;
    unsigned* rel  = sync + 288;
    __builtin_amdgcn_fence(__ATOMIC_RELEASE, "agent");   // wbL2: publish h stores
    unsigned old = __hip_atomic_fetch_add(cnt, 1u, __ATOMIC_RELAXED, __HIP_MEMORY_SCOPE_AGENT);
    if (old == 32u * e - 1u) {                           // last arrival in group
        unsigned og = __hip_atomic_fetch_add(gcnt, 1u, __ATOMIC_RELAXED, __HIP_MEMORY_SCOPE_AGENT);
        if (og == 8u * e - 1u)                           // last group overall
            __hip_atomic_store(rel, e, __ATOMIC_RELAXED, __HIP_MEMORY_SCOPE_AGENT);
    }
    while (__hip_atomic_load(rel, __ATOMIC_RELAXED, __HIP_MEMORY_SCOPE_AGENT) < e)
        __builtin_amdgcn_s_sleep(1);
    __builtin_amdgcn_fence(__ATOMIC_ACQUIRE, "agent");   // inv: see remote h stores
}

// ---------------------------------------------------------------------------
// Kernel 2: recurrent scan (256 blocks x 512 threads, persistent).
// Thread = (b-pair b2 = (tid&31)*2, kh = tid>>5 in [0,16)). Each thread:
// 12 gate rows x 2 b over a 64-wide k-slice; per 4k-chunk: 2 h float4 loads
// (depth-4 software pipeline) + 12 wave-uniform ds_read_b128 + 96 FMA.
// ---------------------------------------------------------------------------
__device__ __forceinline__ float sig_(float x) {
    return 1.f / (1.f + __expf(-x));
}
__device__ __forceinline__ float tanh_(float x) {
    x = fminf(20.f, fmaxf(-20.f, x));
    float e = __expf(-2.f * x);
    return (1.f - e) / (1.f + e);
}

__global__ __launch_bounds__(512, 2) void scan_kernel(const float* __restrict__ gxT,
                                                      const float* __restrict__ w_hh,
                                                      float* __restrict__ hsT2,
                                                      unsigned* __restrict__ sync) {
    __shared__ float wlds[12 * 1024];   // 48 KB: row r = gate*4 + jj
    __shared__ float red[16][12][64];   // 48 KB: [kh][row][b]
    const int tid = threadIdx.x;
    const int bid = blockIdx.x;
    const int b2 = (tid & 31) * 2;                  // k-loop role: b pair base
    const int kh = tid >> 5;                        // k-loop role: [0,16)
    const int b  = tid & 63;                        // epilogue role
    const int jl = (tid >> 6) & 3;                  // epilogue role
    const int jblk = (bid & 7) * 32 + (bid >> 3);   // XCD-contiguous j blocks
    const int j  = jblk * 4 + jl;
    const bool epi = (tid < 256);

    // stage w_hh rows {gate*H + jblk*4 + jj} -> wlds[(gate*4+jj)*1024 + k]
    #pragma unroll
    for (int i = 0; i < 6; ++i) {
        int f = tid + 512 * i;          // [0,3072): 12 rows x 256 float4
        int row = f >> 8;               // [0,12)
        int kq = f & 255;
        float4 v = *(const float4*)&w_hh[((size_t)(row >> 2) * HH + jblk*4 + (row & 3)) * HH + kq*4];
        *(float4*)&wlds[row * 1024 + kq*4] = v;
    }
    __syncthreads();

    // software-pipelined gx registers (step t loaded during step t-1)
    float gx_r = 0.f, gx_z = 0.f, gx_n = 0.f;
    if (epi) {
        size_t off = (size_t)j * 64 + b;            // t = 0
        gx_r = gxT[off];
        gx_z = gxT[off + (size_t)HH * 64];
        gx_n = gxT[off + (size_t)2 * HH * 64];
    }
    float hold = 0.f;                               // h_{t-1}[b][j] register

    for (int t = 0; t < TT; ++t) {
        // prefetch next step's gx early (hidden under the k-loop)
        float nx_r = 0.f, nx_z = 0.f, nx_n = 0.f;
        if (epi && t + 1 < TT) {
            size_t off = ((size_t)(t + 1) * GG + j) * 64 + b;
            nx_r = gxT[off];
            nx_z = gxT[off + (size_t)HH * 64];
            nx_n = gxT[off + (size_t)2 * HH * 64];
        }

        float2 acc[12];
        #pragma unroll
        for (int r = 0; r < 12; ++r) acc[r] = make_float2(0.f, 0.f);

        if (t > 0) {
            // packed h: hsT2[t-1][k4][b][4]; this thread's chunks k4 = kh*16+c
            const float4* __restrict__ base =
                (const float4*)hsT2 + (size_t)(t - 1) * (256 * 64) + (size_t)(kh * 16) * 64;
            float4 ha[4], hb[4];
            #pragma unroll
            for (int c = 0; c < 4; ++c) {           // prime depth-4 pipeline
                ha[c] = base[c * 64 + b2];
                hb[c] = base[c * 64 + b2 + 1];
            }
            #pragma unroll
            for (int c = 0; c < 16; ++c) {          // fully unrolled: static buf idx
                float4 h0 = ha[c & 3], h1 = hb[c & 3];
                if (c + 4 < 16) {
                    ha[c & 3] = base[(c + 4) * 64 + b2];
                    hb[c & 3] = base[(c + 4) * 64 + b2 + 1];
                }
                const float* wp = &wlds[(kh * 16 + c) * 4];
                #pragma unroll
                for (int r = 0; r < 12; ++r) {
                    float4 w4 = *(const float4*)&wp[r * 1024];
                    acc[r].x = fmaf(h0.x, w4.x, acc[r].x);
                    acc[r].x = fmaf(h0.y, w4.y, acc[r].x);
                    acc[r].x = fmaf(h0.z, w4.z, acc[r].x);
                    acc[r].x = fmaf(h0.w, w4.w, acc[r].x);
                    acc[r].y = fmaf(h1.x, w4.x, acc[r].y);
                    acc[r].y = fmaf(h1.y, w4.y, acc[r].y);
                    acc[r].y = fmaf(h1.z, w4.z, acc[r].y);
                    acc[r].y = fmaf(h1.w, w4.w, acc[r].y);
                }
            }
        }
        #pragma unroll
        for (int r = 0; r < 12; ++r) *(float2*)&red[kh][r][b2] = acc[r];
        __syncthreads();

        if (epi) {
            float gr = 0.f, gz = 0.f, gn = 0.f;
            #pragma unroll
            for (int k2 = 0; k2 < 16; ++k2) {
                gr += red[k2][0 + jl][b];
                gz += red[k2][4 + jl][b];
                gn += red[k2][8 + jl][b];
            }
            float r = sig_(gx_r + gr);
            float z = sig_(gx_z + gz);
            float n = tanh_(gx_n + r * gn);
            float hnew = (1.f - z) * n + z * hold;
            hsT2[(((size_t)t * 256 + jblk) * 64 + b) * 4 + jl] = hnew;  // [t][jblk][b][jl]
            hold = hnew;
        }
        __syncthreads();                            // drains all waves' stores (vmcnt 0)

        if (t + 1 < TT) {
            if (tid == 0) grid_barrier(sync, bid, (unsigned)(t + 1));
            __syncthreads();
            if (epi) { gx_r = nx_r; gx_z = nx_z; gx_n = nx_n; }
        }
    }
}

// ---------------------------------------------------------------------------
// Kernel 3: out[b][t][g] = sum_k hsT2[t][k>>2][b][k&3] * w_proj[g][k]
// ---------------------------------------------------------------------------
__global__ __launch_bounds__(256) void proj_gemm(const float* __restrict__ hsT2,
                                                 const float* __restrict__ w_proj,
                                                 float* __restrict__ out) {
    __shared__ float As2[8][64][4];   // [k4][b][ki] packed copy (8 KB)
    __shared__ float Bs[BK][68];      // [k][g]
    const int tid = threadIdx.x;
    const int bx = blockIdx.x;     // g tile (16)
    const int by = blockIdx.y;     // t (512)
    const int tx = tid & 15, ty = tid >> 4;
    float acc[4][4] = {};

    const float4* __restrict__ hp4 = (const float4*)hsT2 + (size_t)by * ((HH / 4) * BB);

    for (int k0 = 0; k0 < HH; k0 += BK) {
        #pragma unroll
        for (int i = 0; i < 2; ++i) {
            int f = tid + 256 * i;          // [0,512): 8 k4-blocks x 64 b
            int k4l = f >> 6, bb = f & 63;
            float4 v = hp4[((size_t)(k0 >> 2) + k4l) * 64 + bb];
            *(float4*)&As2[k4l][bb][0] = v;
            int wrow = f >> 3, kq = f & 7;  // [0,512): 64 g-rows x 8 float4
            float4 w = *(const float4*)&w_proj[(size_t)(bx*64 + wrow) * HH + k0 + kq * 4];
            Bs[kq*4+0][wrow] = w.x; Bs[kq*4+1][wrow] = w.y;
            Bs[kq*4+2][wrow] = w.z; Bs[kq*4+3][wrow] = w.w;
        }
        __syncthreads();
        #pragma unroll
        for (int k4 = 0; k4 < 8; ++k4) {
            float4 a4[4];
            #pragma unroll
            for (int i = 0; i < 4; ++i) a4[i] = *(const float4*)&As2[k4][ty*4 + i][0];
            float4 b4[4];
            #pragma unroll
            for (int kk = 0; kk < 4; ++kk) b4[kk] = *(const float4*)&Bs[k4*4 + kk][tx*4];
            #pragma unroll
            for (int i = 0; i < 4; ++i) {
                float a[4] = {a4[i].x, a4[i].y, a4[i].z, a4[i].w};
                #pragma unroll
                for (int jj = 0; jj < 4; ++jj) {
                    float b0 = (jj == 0) ? b4[0].x : (jj == 1) ? b4[0].y : (jj == 2) ? b4[0].z : b4[0].w;
                    float b1 = (jj == 0) ? b4[1].x : (jj == 1) ? b4[1].y : (jj == 2) ? b4[1].z : b4[1].w;
                    float b2 = (jj == 0) ? b4[2].x : (jj == 1) ? b4[2].y : (jj == 2) ? b4[2].z : b4[2].w;
                    float b3 = (jj == 0) ? b4[3].x : (jj == 1) ? b4[3].y : (jj == 2) ? b4[3].z : b4[3].w;
                    acc[i][jj] = fmaf(a[0], b0, acc[i][jj]);
                    acc[i][jj] = fmaf(a[1], b1, acc[i][jj]);
                    acc[i][jj] = fmaf(a[2], b2, acc[i][jj]);
                    acc[i][jj] = fmaf(a[3], b3, acc[i][jj]);
                }
            }
        }
        __syncthreads();
    }
    #pragma unroll
    for (int i = 0; i < 4; ++i) {
        float4 o = make_float4(acc[i][0], acc[i][1], acc[i][2], acc[i][3]);
        *(float4*)&out[((size_t)(ty*4 + i) * TT + by) * HH + bx*64 + tx*4] = o;
    }
}

// ---------------------------------------------------------------------------
extern "C" void kernel_launch(void* const* d_in, const int* in_sizes, int n_in,
                              void* d_out, int out_size, void* d_ws, size_t ws_size,
                              hipStream_t stream) {
    const float* x      = (const float*)d_in[0];
    const float* w_ih   = (const float*)d_in[1];
    const float* w_hh   = (const float*)d_in[2];
    const float* w_proj = (const float*)d_in[3];
    float* out = (float*)d_out;

    if (ws_size < (GX_ELEMS + HS_ELEMS) * sizeof(float)) return;  // need 512 MB

    float* gxbuf = (float*)d_ws;
    float* hsbuf = gxbuf + GX_ELEMS;

    // barrier state lives in d_out (proj overwrites it afterwards)
    hipMemsetAsync(d_out, 0, 4096, stream);

    gx_gemm<<<dim3(48, 512), 256, 0, stream>>>(x, w_ih, gxbuf);

    const float* gx_p = gxbuf;
    const float* whh_p = w_hh;
    float* hs_p = hsbuf;
    unsigned* sync_p = (unsigned*)d_out;
    void* args[] = {(void*)&gx_p, (void*)&whh_p, (void*)&hs_p, (void*)&sync_p};
    hipLaunchCooperativeKernel((void*)scan_kernel, dim3(256), dim3(512), args, 0, stream);

    proj_gemm<<<dim3(16, 512), 256, 0, stream>>>(hsbuf, w_proj, out);
}